// Round 1
// baseline (28.143 us; speedup 1.0000x reference)
//
#include <hip/hip_runtime.h>
#include <math.h>

#define HH 256
#define WW 256
#define NPTS 1024
#define NG 2
#define RANK 6
#define NC 128
#define PIX (HH * WW)
#define SIGMA_CUT 18.0f

// ---------------------------------------------------------------------------
// Kernel 1: zero the abundance accumulator + compute E = clip(endmember +
// 0.1*tanh(s)*tanh(U@V), 1e-6).
// ---------------------------------------------------------------------------
__global__ __launch_bounds__(256) void init_kernel(
    const float* __restrict__ lora_U, const float* __restrict__ lora_V,
    const float* __restrict__ lora_scale_logit,
    const float* __restrict__ endmember,
    float* __restrict__ abund, float* __restrict__ Eout)
{
    int i = blockIdx.x * 256 + threadIdx.x;
    if (i < PIX * RANK) abund[i] = 0.0f;
    if (i < RANK * NC) {
        int r = i / NC;
        int c = i - r * NC;
        float dot = lora_U[r * 2 + 0] * lora_V[c] +
                    lora_U[r * 2 + 1] * lora_V[NC + c];
        float scale = 0.1f * tanhf(lora_scale_logit[0]);
        float e = endmember[i] + scale * tanhf(dot);
        Eout[i] = fmaxf(e, 1e-6f);
    }
}

__device__ __forceinline__ float softplus_f(float x) {
    // numerically stable log(1+exp(x))
    return fmaxf(x, 0.0f) + log1pf(expf(-fabsf(x)));
}

// ---------------------------------------------------------------------------
// Kernel 2: scatter-splat. One 64-thread block per gaussian. Compute the
// bounding box where sigma <= SIGMA_CUT (beyond it exp(-sigma) contributes
// < 3*exp(-18)*0.05 ~ 2e-9 per pixel; summed over 1024 gaussians << 2e-2
// threshold) and atomicAdd the RANK feature values into abundance[p][r].
// ---------------------------------------------------------------------------
__global__ __launch_bounds__(64) void splat_kernel(
    const float* __restrict__ xyz, const float* __restrict__ cholesky,
    const float* __restrict__ features_dc,
    const float* __restrict__ gabor_freqs,
    const float* __restrict__ gabor_weights,
    const float* __restrict__ opacity,
    float* __restrict__ abund)
{
    const int n = blockIdx.x;
    const int lane = threadIdx.x;

    // per-gaussian scalars (computed redundantly by all 64 lanes -- cheap)
    float mx = tanhf(xyz[n * 2 + 0]);
    float my = tanhf(xyz[n * 2 + 1]);
    float cx = (mx * 0.5f + 0.5f) * (float)WW;
    float cy = (my * 0.5f + 0.5f) * (float)HH;

    float l1 = cholesky[n * 3 + 0] + 0.5f;
    float l2 = cholesky[n * 3 + 1];
    float l3 = cholesky[n * 3 + 2] + 0.5f;
    float a = l1 * l1;
    float b = l1 * l2;
    float c = l2 * l2 + l3 * l3;
    float det = a * c - b * b;
    float inv = 1.0f / det;
    float ca = c * inv;
    float cb = -b * inv;
    float cc = a * inv;

    float feats[RANK];
    float op = opacity[n];
#pragma unroll
    for (int r = 0; r < RANK; ++r)
        feats[r] = softplus_f(features_dc[n * RANK + r]) * op;

    float fx0 = expf(gabor_freqs[(n * NG + 0) * 2 + 0]);
    float fy0 = expf(gabor_freqs[(n * NG + 0) * 2 + 1]);
    float fx1 = expf(gabor_freqs[(n * NG + 1) * 2 + 0]);
    float fy1 = expf(gabor_freqs[(n * NG + 1) * 2 + 1]);
    float gw0 = 1.0f / (1.0f + expf(-gabor_weights[n * NG + 0]));
    float gw1 = 1.0f / (1.0f + expf(-gabor_weights[n * NG + 1]));

    // bbox: |dx| <= sqrt(2*T*Sigma_xx) = sqrt(2*T*a); |dy| <= sqrt(2*T*c)
    float rx = sqrtf(fmaxf(2.0f * SIGMA_CUT * a, 0.0f));
    float ry = sqrtf(fmaxf(2.0f * SIGMA_CUT * c, 0.0f));
    int x0 = max(0, (int)floorf(cx - rx - 0.5f));
    int x1 = min(WW - 1, (int)ceilf(cx + rx - 0.5f));
    int y0 = max(0, (int)floorf(cy - ry - 0.5f));
    int y1 = min(HH - 1, (int)ceilf(cy + ry - 0.5f));
    int bw = x1 - x0 + 1;
    int bh = y1 - y0 + 1;
    if (bw <= 0 || bh <= 0) return;
    int total = bw * bh;

    for (int t = lane; t < total; t += 64) {
        int x = x0 + (t % bw);
        int y = y0 + (t / bw);
        float dx = ((float)x + 0.5f) - cx;
        float dy = ((float)y + 0.5f) - cy;
        float sigma = 0.5f * (ca * dx * dx + cc * dy * dy) + cb * dx * dy;
        if (sigma < 0.0f || sigma > SIGMA_CUT) continue;
        float gauss = expf(-sigma);
        float mod = 1.0f + gw0 * cosf(fx0 * dx + fy0 * dy)
                         + gw1 * cosf(fx1 * dx + fy1 * dy);
        float wm = gauss * mod;
        float* dst = abund + (size_t)(y * WW + x) * RANK;
#pragma unroll
        for (int r = 0; r < RANK; ++r)
            atomicAdd(dst + r, wm * feats[r]);
    }
}

// ---------------------------------------------------------------------------
// Kernel 3: render[c][p] = sum_r max(abund[p][r],0) * E[r][c].
// grid (PIX/1024, NC/16), 256 threads. Each thread: 4 consecutive pixels,
// 16 channels, float4 loads + float4 coalesced stores.
// blockIdx.y == 0 also writes the clamped abundance back (the reference
// returns max(abundance,0)).
// ---------------------------------------------------------------------------
__global__ __launch_bounds__(256) void render_kernel(
    const float* __restrict__ abund, const float* __restrict__ E,
    float* __restrict__ render, float* __restrict__ abund_out)
{
    __shared__ float Es[RANK * 16];
    const int tid = threadIdx.x;
    const int cbase = blockIdx.y * 16;
    if (tid < RANK * 16) {
        int r = tid / 16;
        int cc = tid - r * 16;
        Es[tid] = E[r * NC + cbase + cc];
    }
    __syncthreads();

    const int pp = blockIdx.x * 1024 + tid * 4;  // 4 consecutive pixels

    float ab[24];
    const float4* av = (const float4*)(abund + (size_t)pp * RANK);
#pragma unroll
    for (int v = 0; v < 6; ++v) {
        float4 t = av[v];
        ab[v * 4 + 0] = fmaxf(t.x, 0.0f);
        ab[v * 4 + 1] = fmaxf(t.y, 0.0f);
        ab[v * 4 + 2] = fmaxf(t.z, 0.0f);
        ab[v * 4 + 3] = fmaxf(t.w, 0.0f);
    }

    if (blockIdx.y == 0) {
        // write clamped abundance output (only one channel-group block does it)
        float4* ao = (float4*)(abund_out + (size_t)pp * RANK);
#pragma unroll
        for (int v = 0; v < 6; ++v)
            ao[v] = make_float4(ab[v * 4 + 0], ab[v * 4 + 1],
                                ab[v * 4 + 2], ab[v * 4 + 3]);
    }

#pragma unroll
    for (int cc = 0; cc < 16; ++cc) {
        int c = cbase + cc;
        float o0 = 0.0f, o1 = 0.0f, o2 = 0.0f, o3 = 0.0f;
#pragma unroll
        for (int r = 0; r < RANK; ++r) {
            float e = Es[r * 16 + cc];
            o0 = fmaf(ab[0 * 6 + r], e, o0);
            o1 = fmaf(ab[1 * 6 + r], e, o1);
            o2 = fmaf(ab[2 * 6 + r], e, o2);
            o3 = fmaf(ab[3 * 6 + r], e, o3);
        }
        *((float4*)(render + (size_t)c * PIX + pp)) = make_float4(o0, o1, o2, o3);
    }
}

extern "C" void kernel_launch(void* const* d_in, const int* in_sizes, int n_in,
                              void* d_out, int out_size, void* d_ws, size_t ws_size,
                              hipStream_t stream)
{
    const float* xyz             = (const float*)d_in[0];
    const float* cholesky        = (const float*)d_in[1];
    const float* features_dc     = (const float*)d_in[2];
    const float* gabor_freqs     = (const float*)d_in[3];
    const float* gabor_weights   = (const float*)d_in[4];
    const float* lora_U          = (const float*)d_in[5];
    const float* lora_V          = (const float*)d_in[6];
    const float* lora_scale_logit= (const float*)d_in[7];
    const float* opacity         = (const float*)d_in[8];
    const float* endmember       = (const float*)d_in[9];

    float* out    = (float*)d_out;
    float* render = out;                               // NC*PIX
    float* abund  = out + (size_t)NC * PIX;            // PIX*RANK
    float* Eout   = abund + (size_t)PIX * RANK;        // RANK*NC

    init_kernel<<<(PIX * RANK + 255) / 256, 256, 0, stream>>>(
        lora_U, lora_V, lora_scale_logit, endmember, abund, Eout);

    splat_kernel<<<NPTS, 64, 0, stream>>>(
        xyz, cholesky, features_dc, gabor_freqs, gabor_weights, opacity, abund);

    render_kernel<<<dim3(PIX / 1024, NC / 16), 256, 0, stream>>>(
        abund, Eout, render, abund);
}

// Round 3
// 27.795 us; speedup vs baseline: 1.0125x; 1.0125x over previous
//
#include <hip/hip_runtime.h>
#include <math.h>

#define HH 256
#define WW 256
#define NPTS 1024
#define NG 2
#define RANK 6
#define NC 128
#define PIX (HH * WW)
#define SIGMA_CUT 18.0f

typedef float vf4 __attribute__((ext_vector_type(4)));  // clang vector: valid for __builtin_nontemporal_store

// ---------------------------------------------------------------------------
// Kernel 1: zero the abundance accumulator + compute E = clip(endmember +
// 0.1*tanh(s)*tanh(U@V), 1e-6).
// ---------------------------------------------------------------------------
__global__ __launch_bounds__(256) void init_kernel(
    const float* __restrict__ lora_U, const float* __restrict__ lora_V,
    const float* __restrict__ lora_scale_logit,
    const float* __restrict__ endmember,
    float* __restrict__ abund, float* __restrict__ Eout)
{
    int i = blockIdx.x * 256 + threadIdx.x;
    if (i < PIX * RANK) abund[i] = 0.0f;
    if (i < RANK * NC) {
        int r = i / NC;
        int c = i - r * NC;
        float dot = lora_U[r * 2 + 0] * lora_V[c] +
                    lora_U[r * 2 + 1] * lora_V[NC + c];
        float scale = 0.1f * tanhf(lora_scale_logit[0]);
        float e = endmember[i] + scale * tanhf(dot);
        Eout[i] = fmaxf(e, 1e-6f);
    }
}

__device__ __forceinline__ float softplus_f(float x) {
    return fmaxf(x, 0.0f) + log1pf(expf(-fabsf(x)));
}

// ---------------------------------------------------------------------------
// Kernel 2: scatter-splat. One 64-thread block per gaussian. Pixels beyond
// sigma > SIGMA_CUT contribute < 2e-9 each (<< 2e-2 threshold summed).
// ---------------------------------------------------------------------------
__global__ __launch_bounds__(64) void splat_kernel(
    const float* __restrict__ xyz, const float* __restrict__ cholesky,
    const float* __restrict__ features_dc,
    const float* __restrict__ gabor_freqs,
    const float* __restrict__ gabor_weights,
    const float* __restrict__ opacity,
    float* __restrict__ abund)
{
    const int n = blockIdx.x;
    const int lane = threadIdx.x;

    float mx = tanhf(xyz[n * 2 + 0]);
    float my = tanhf(xyz[n * 2 + 1]);
    float cx = (mx * 0.5f + 0.5f) * (float)WW;
    float cy = (my * 0.5f + 0.5f) * (float)HH;

    float l1 = cholesky[n * 3 + 0] + 0.5f;
    float l2 = cholesky[n * 3 + 1];
    float l3 = cholesky[n * 3 + 2] + 0.5f;
    float a = l1 * l1;
    float b = l1 * l2;
    float c = l2 * l2 + l3 * l3;
    float det = a * c - b * b;
    float inv = 1.0f / det;
    float ca = c * inv;
    float cb = -b * inv;
    float cc = a * inv;

    float feats[RANK];
    float op = opacity[n];
#pragma unroll
    for (int r = 0; r < RANK; ++r)
        feats[r] = softplus_f(features_dc[n * RANK + r]) * op;

    float fx0 = expf(gabor_freqs[(n * NG + 0) * 2 + 0]);
    float fy0 = expf(gabor_freqs[(n * NG + 0) * 2 + 1]);
    float fx1 = expf(gabor_freqs[(n * NG + 1) * 2 + 0]);
    float fy1 = expf(gabor_freqs[(n * NG + 1) * 2 + 1]);
    float gw0 = 1.0f / (1.0f + expf(-gabor_weights[n * NG + 0]));
    float gw1 = 1.0f / (1.0f + expf(-gabor_weights[n * NG + 1]));

    float rx = sqrtf(fmaxf(2.0f * SIGMA_CUT * a, 0.0f));
    float ry = sqrtf(fmaxf(2.0f * SIGMA_CUT * c, 0.0f));
    int x0 = max(0, (int)floorf(cx - rx - 0.5f));
    int x1 = min(WW - 1, (int)ceilf(cx + rx - 0.5f));
    int y0 = max(0, (int)floorf(cy - ry - 0.5f));
    int y1 = min(HH - 1, (int)ceilf(cy + ry - 0.5f));
    int bw = x1 - x0 + 1;
    int bh = y1 - y0 + 1;
    if (bw <= 0 || bh <= 0) return;
    int total = bw * bh;

    for (int t = lane; t < total; t += 64) {
        int x = x0 + (t % bw);
        int y = y0 + (t / bw);
        float dx = ((float)x + 0.5f) - cx;
        float dy = ((float)y + 0.5f) - cy;
        float sigma = 0.5f * (ca * dx * dx + cc * dy * dy) + cb * dx * dy;
        if (sigma < 0.0f || sigma > SIGMA_CUT) continue;
        float gauss = expf(-sigma);
        float mod = 1.0f + gw0 * cosf(fx0 * dx + fy0 * dy)
                         + gw1 * cosf(fx1 * dx + fy1 * dy);
        float wm = gauss * mod;
        float* dst = abund + (size_t)(y * WW + x) * RANK;
#pragma unroll
        for (int r = 0; r < RANK; ++r)
            atomicAdd(dst + r, wm * feats[r]);
    }
}

// ---------------------------------------------------------------------------
// Kernel 3: render[c][p] = sum_r max(abund[p][r],0) * E[r][c].
// grid (PIX/1024, NC/8) = 1024 blocks, 256 threads: 4 px x 8 ch per thread.
// Nontemporal stores for the 33.5 MB write-once render stream so the abund
// re-reads (16x, ~25 MB) stay L2-resident.
// ---------------------------------------------------------------------------
__global__ __launch_bounds__(256) void render_kernel(
    const float* __restrict__ abund, const float* __restrict__ E,
    float* __restrict__ render, float* __restrict__ abund_out)
{
    __shared__ float Es[RANK * 8];
    const int tid = threadIdx.x;
    const int cbase = blockIdx.y * 8;
    if (tid < RANK * 8) {
        int r = tid / 8;
        int cc = tid - r * 8;
        Es[tid] = E[r * NC + cbase + cc];
    }
    __syncthreads();

    const int pp = blockIdx.x * 1024 + tid * 4;  // 4 consecutive pixels

    float ab[24];
    const float4* av = (const float4*)(abund + (size_t)pp * RANK);
#pragma unroll
    for (int v = 0; v < 6; ++v) {
        float4 t = av[v];
        ab[v * 4 + 0] = fmaxf(t.x, 0.0f);
        ab[v * 4 + 1] = fmaxf(t.y, 0.0f);
        ab[v * 4 + 2] = fmaxf(t.z, 0.0f);
        ab[v * 4 + 3] = fmaxf(t.w, 0.0f);
    }

    if (blockIdx.y == 0) {
        vf4* ao = (vf4*)(abund_out + (size_t)pp * RANK);
#pragma unroll
        for (int v = 0; v < 6; ++v) {
            vf4 t = { ab[v * 4 + 0], ab[v * 4 + 1], ab[v * 4 + 2], ab[v * 4 + 3] };
            __builtin_nontemporal_store(t, ao + v);
        }
    }

#pragma unroll
    for (int cc = 0; cc < 8; ++cc) {
        int c = cbase + cc;
        float o0 = 0.0f, o1 = 0.0f, o2 = 0.0f, o3 = 0.0f;
#pragma unroll
        for (int r = 0; r < RANK; ++r) {
            float e = Es[r * 8 + cc];
            o0 = fmaf(ab[0 * 6 + r], e, o0);
            o1 = fmaf(ab[1 * 6 + r], e, o1);
            o2 = fmaf(ab[2 * 6 + r], e, o2);
            o3 = fmaf(ab[3 * 6 + r], e, o3);
        }
        vf4 t = { o0, o1, o2, o3 };
        __builtin_nontemporal_store(t, (vf4*)(render + (size_t)c * PIX + pp));
    }
}

extern "C" void kernel_launch(void* const* d_in, const int* in_sizes, int n_in,
                              void* d_out, int out_size, void* d_ws, size_t ws_size,
                              hipStream_t stream)
{
    const float* xyz             = (const float*)d_in[0];
    const float* cholesky        = (const float*)d_in[1];
    const float* features_dc     = (const float*)d_in[2];
    const float* gabor_freqs     = (const float*)d_in[3];
    const float* gabor_weights   = (const float*)d_in[4];
    const float* lora_U          = (const float*)d_in[5];
    const float* lora_V          = (const float*)d_in[6];
    const float* lora_scale_logit= (const float*)d_in[7];
    const float* opacity         = (const float*)d_in[8];
    const float* endmember       = (const float*)d_in[9];

    float* out    = (float*)d_out;
    float* render = out;                               // NC*PIX
    float* abund  = out + (size_t)NC * PIX;            // PIX*RANK
    float* Eout   = abund + (size_t)PIX * RANK;        // RANK*NC

    init_kernel<<<(PIX * RANK + 255) / 256, 256, 0, stream>>>(
        lora_U, lora_V, lora_scale_logit, endmember, abund, Eout);

    splat_kernel<<<NPTS, 64, 0, stream>>>(
        xyz, cholesky, features_dc, gabor_freqs, gabor_weights, opacity, abund);

    render_kernel<<<dim3(PIX / 1024, NC / 8), 256, 0, stream>>>(
        abund, Eout, render, abund);
}